// Round 3
// baseline (451.419 us; speedup 1.0000x reference)
//
#include <hip/hip_runtime.h>
#include <hip/hip_bf16.h>

#define MODEL_DIM 256
#define HIST 8
#define HID 512
#define NNEUR 64
#define IN_DIM 2304   // MODEL_DIM * (1 + HIST)
#define BATCH 32

__device__ __forceinline__ float geluf(float x) {
    return 0.5f * x * (1.0f + erff(x * 0.70710678118654752440f));
}

// ---------------------------------------------------------------------------
// K0: x[b][0:256] = emb[b] @ Wp + bp ; x[b][256:2304] = pre_activations flat
// grid 32 (b), block 256 (d). Output x is f32 in ws.
// ---------------------------------------------------------------------------
__global__ __launch_bounds__(256) void k_build_x(
        const float* __restrict__ emb, const float* __restrict__ pre,
        const float* __restrict__ Wp, const float* __restrict__ bp,
        float* __restrict__ x) {
    const int b = blockIdx.x;
    const int d = threadIdx.x;

    __shared__ float e[MODEL_DIM];
    e[d] = emb[b * MODEL_DIM + d];
    __syncthreads();

    float acc = bp[d];
    #pragma unroll 4
    for (int k = 0; k < MODEL_DIM; ++k)
        acc = fmaf(e[k], Wp[(size_t)k * MODEL_DIM + d], acc);
    x[b * IN_DIM + d] = acc;

    #pragma unroll
    for (int r = 0; r < HIST; ++r)
        x[b * IN_DIM + MODEL_DIM + r * MODEL_DIM + d] = pre[r * MODEL_DIM + d];
}

// ---------------------------------------------------------------------------
// K1: layer1 partials. grid 256 = n(64) x ntile(2: 256 cols) x kslice(2: 1152)
// block 256: thread = colgroup(64, 4 cols each) x batchgroup(4, 8 rows each)
// p1[ks][n][b][h] f32
// ---------------------------------------------------------------------------
__global__ __launch_bounds__(256, 2) void k_layer1(
        const float* __restrict__ x, const float* __restrict__ W1,
        float* __restrict__ p1) {
    const int bid = blockIdx.x;
    const int n  = bid >> 2;
    const int nt = (bid >> 1) & 1;
    const int ks = bid & 1;
    const int t  = threadIdx.x;
    const int cg = t & 63;
    const int bg = t >> 6;
    const int col0  = nt * 256 + cg * 4;
    const int brow0 = bg * 8;

    const float* W = W1 + (size_t)n * IN_DIM * HID;

    float acc[8][4];
    #pragma unroll
    for (int i = 0; i < 8; ++i)
        #pragma unroll
        for (int j = 0; j < 4; ++j) acc[i][j] = 0.0f;

    __shared__ float xs[BATCH][128];
    const int k0 = ks * 1152;
    for (int kc = 0; kc < 1152; kc += 128) {
        __syncthreads();
        #pragma unroll
        for (int q = 0; q < 4; ++q) {            // 32*128 f32 = 1024 float4
            int fi  = t + 256 * q;
            int row = fi >> 5;
            int c4  = fi & 31;
            float4 v = ((const float4*)(x + (size_t)row * IN_DIM + k0 + kc))[c4];
            ((float4*)&xs[row][0])[c4] = v;
        }
        __syncthreads();
        const float* Wk = W + (size_t)(k0 + kc) * HID + col0;
        #pragma unroll 2
        for (int kk = 0; kk < 128; ++kk) {
            float4 w = *((const float4*)(Wk + (size_t)kk * HID));
            #pragma unroll
            for (int i = 0; i < 8; ++i) {
                float xv = xs[brow0 + i][kk];
                acc[i][0] = fmaf(xv, w.x, acc[i][0]);
                acc[i][1] = fmaf(xv, w.y, acc[i][1]);
                acc[i][2] = fmaf(xv, w.z, acc[i][2]);
                acc[i][3] = fmaf(xv, w.w, acc[i][3]);
            }
        }
    }
    float* P = p1 + (size_t)(ks * NNEUR + n) * BATCH * HID;
    #pragma unroll
    for (int i = 0; i < 8; ++i)
        *((float4*)(P + (size_t)(brow0 + i) * HID + col0)) =
            make_float4(acc[i][0], acc[i][1], acc[i][2], acc[i][3]);
}

// ---------------------------------------------------------------------------
// K2: layer2. h1 = gelu(p1[0]+p1[1]+b1) staged on the fly.
// grid 256 = n(64) x ntile(2) x kslice(2: K 256 each). p2[ks][n][b][g] f32
// ---------------------------------------------------------------------------
__global__ __launch_bounds__(256, 2) void k_layer2(
        const float* __restrict__ p1, const float* __restrict__ b1,
        const float* __restrict__ W2, float* __restrict__ p2) {
    const int bid = blockIdx.x;
    const int n  = bid >> 2;
    const int nt = (bid >> 1) & 1;
    const int ks = bid & 1;
    const int t  = threadIdx.x;
    const int cg = t & 63;
    const int bg = t >> 6;
    const int col0  = nt * 256 + cg * 4;
    const int brow0 = bg * 8;

    const float* W    = W2 + (size_t)n * HID * HID;
    const float* bias = b1 + (size_t)n * HID;

    float acc[8][4];
    #pragma unroll
    for (int i = 0; i < 8; ++i)
        #pragma unroll
        for (int j = 0; j < 4; ++j) acc[i][j] = 0.0f;

    __shared__ float xs[BATCH][128];
    for (int kc = 0; kc < 256; kc += 128) {
        const int kbase = ks * 256 + kc;
        __syncthreads();
        #pragma unroll
        for (int q = 0; q < 4; ++q) {
            int fi  = t + 256 * q;
            int row = fi >> 5;
            int c4  = fi & 31;
            const float* a0 = p1 + ((size_t)n * BATCH + row) * HID + kbase;
            const float* a1 = a0 + (size_t)NNEUR * BATCH * HID;
            float4 v0 = ((const float4*)a0)[c4];
            float4 v1 = ((const float4*)a1)[c4];
            float4 bb = *((const float4*)(bias + kbase + c4 * 4));
            ((float4*)&xs[row][0])[c4] = make_float4(
                geluf(v0.x + v1.x + bb.x),
                geluf(v0.y + v1.y + bb.y),
                geluf(v0.z + v1.z + bb.z),
                geluf(v0.w + v1.w + bb.w));
        }
        __syncthreads();
        const float* Wk = W + (size_t)kbase * HID + col0;
        #pragma unroll 2
        for (int kk = 0; kk < 128; ++kk) {
            float4 w = *((const float4*)(Wk + (size_t)kk * HID));
            #pragma unroll
            for (int i = 0; i < 8; ++i) {
                float xv = xs[brow0 + i][kk];
                acc[i][0] = fmaf(xv, w.x, acc[i][0]);
                acc[i][1] = fmaf(xv, w.y, acc[i][1]);
                acc[i][2] = fmaf(xv, w.z, acc[i][2]);
                acc[i][3] = fmaf(xv, w.w, acc[i][3]);
            }
        }
    }
    float* P = p2 + (size_t)(ks * NNEUR + n) * BATCH * HID;
    #pragma unroll
    for (int i = 0; i < 8; ++i)
        *((float4*)(P + (size_t)(brow0 + i) * HID + col0)) =
            make_float4(acc[i][0], acc[i][1], acc[i][2], acc[i][3]);
}

// ---------------------------------------------------------------------------
// K3: layer3. h2 = gelu(p2[0]+p2[1]+b2). grid 256 = n(64) x kslice(4: K 128)
// all 256 output cols in one block. p3[ks][n][b][d] f32
// ---------------------------------------------------------------------------
__global__ __launch_bounds__(256, 2) void k_layer3(
        const float* __restrict__ p2, const float* __restrict__ b2,
        const float* __restrict__ W3, float* __restrict__ p3) {
    const int n  = blockIdx.x >> 2;
    const int ks = blockIdx.x & 3;
    const int t  = threadIdx.x;
    const int cg = t & 63;
    const int bg = t >> 6;
    const int col0  = cg * 4;
    const int brow0 = bg * 8;

    const float* W    = W3 + (size_t)n * HID * MODEL_DIM;
    const float* bias = b2 + (size_t)n * HID;
    const int kbase = ks * 128;

    float acc[8][4];
    #pragma unroll
    for (int i = 0; i < 8; ++i)
        #pragma unroll
        for (int j = 0; j < 4; ++j) acc[i][j] = 0.0f;

    __shared__ float xs[BATCH][128];
    #pragma unroll
    for (int q = 0; q < 4; ++q) {
        int fi  = t + 256 * q;
        int row = fi >> 5;
        int c4  = fi & 31;
        const float* a0 = p2 + ((size_t)n * BATCH + row) * HID + kbase;
        const float* a1 = a0 + (size_t)NNEUR * BATCH * HID;
        float4 v0 = ((const float4*)a0)[c4];
        float4 v1 = ((const float4*)a1)[c4];
        float4 bb = *((const float4*)(bias + kbase + c4 * 4));
        ((float4*)&xs[row][0])[c4] = make_float4(
            geluf(v0.x + v1.x + bb.x),
            geluf(v0.y + v1.y + bb.y),
            geluf(v0.z + v1.z + bb.z),
            geluf(v0.w + v1.w + bb.w));
    }
    __syncthreads();
    const float* Wk = W + (size_t)kbase * MODEL_DIM + col0;
    #pragma unroll 2
    for (int kk = 0; kk < 128; ++kk) {
        float4 w = *((const float4*)(Wk + (size_t)kk * MODEL_DIM));
        #pragma unroll
        for (int i = 0; i < 8; ++i) {
            float xv = xs[brow0 + i][kk];
            acc[i][0] = fmaf(xv, w.x, acc[i][0]);
            acc[i][1] = fmaf(xv, w.y, acc[i][1]);
            acc[i][2] = fmaf(xv, w.z, acc[i][2]);
            acc[i][3] = fmaf(xv, w.w, acc[i][3]);
        }
    }
    float* P = p3 + (size_t)(ks * NNEUR + n) * BATCH * MODEL_DIM;
    #pragma unroll
    for (int i = 0; i < 8; ++i)
        *((float4*)(P + (size_t)(brow0 + i) * MODEL_DIM + col0)) =
            make_float4(acc[i][0], acc[i][1], acc[i][2], acc[i][3]);
}

// ---------------------------------------------------------------------------
// K4: y = sum(p3[0..3]) + b3 ; LayerNorm ; oscillator mod ; f32 store
// grid 512 = n(64) x bquad(8); block 256 = 4 waves, wave w -> batch row
// ---------------------------------------------------------------------------
__global__ __launch_bounds__(256) void k_final(
        const float* __restrict__ p3, const float* __restrict__ b3,
        const float* __restrict__ gamma, const float* __restrict__ beta,
        const int* __restrict__ tick, float* __restrict__ out) {
    const int n  = blockIdx.x >> 3;
    const int bq = blockIdx.x & 7;
    const int t  = threadIdx.x;
    const int w  = t >> 6;
    const int lane = t & 63;
    const int b  = bq * 4 + w;

    const size_t par0 = (size_t)n * MODEL_DIM;
    const size_t rowoff = ((size_t)n * BATCH + b) * MODEL_DIM;
    const size_t sl = (size_t)NNEUR * BATCH * MODEL_DIM;

    float y[4];
    #pragma unroll
    for (int j = 0; j < 4; ++j) {
        int d = lane + 64 * j;
        float v = b3[par0 + d];
        v += p3[rowoff + d];
        v += p3[sl + rowoff + d];
        v += p3[2 * sl + rowoff + d];
        v += p3[3 * sl + rowoff + d];
        y[j] = v;
    }
    float s = y[0] + y[1] + y[2] + y[3];
    #pragma unroll
    for (int off = 32; off > 0; off >>= 1) s += __shfl_xor(s, off);
    float mu = s * (1.0f / 256.0f);
    float q = 0.0f;
    #pragma unroll
    for (int j = 0; j < 4; ++j) { float d0 = y[j] - mu; q = fmaf(d0, d0, q); }
    #pragma unroll
    for (int off = 32; off > 0; off >>= 1) q += __shfl_xor(q, off);
    float inv = rsqrtf(q * (1.0f / 256.0f) + 1e-5f);

    const double TWO_PI = 6.283185307179586476925287;
    double freq  = 0.5 * pow(80.0, (double)n * (1.0 / 63.0));
    double phase = fmod((double)n * 2.3571, TWO_PI);
    double tt    = (double)(*tick) * 0.1;
    float mod = (float)(1.0 + 0.5 * sin(TWO_PI * freq * tt + phase));

    #pragma unroll
    for (int j = 0; j < 4; ++j) {
        int d = lane + 64 * j;
        float o = (y[j] - mu) * inv * gamma[par0 + d] + beta[par0 + d];
        o *= mod;
        out[((size_t)b * NNEUR + n) * MODEL_DIM + d] = o;
    }
}

// ---------------------------------------------------------------------------
extern "C" void kernel_launch(void* const* d_in, const int* in_sizes, int n_in,
                              void* d_out, int out_size, void* d_ws, size_t ws_size,
                              hipStream_t stream) {
    const float* emb  = (const float*)d_in[0];
    const float* pre  = (const float*)d_in[1];
    const float* Wp   = (const float*)d_in[2];
    const float* bp   = (const float*)d_in[3];
    const float* W1   = (const float*)d_in[4];
    const float* b1   = (const float*)d_in[5];
    const float* W2   = (const float*)d_in[6];
    const float* b2   = (const float*)d_in[7];
    const float* W3   = (const float*)d_in[8];
    const float* b3   = (const float*)d_in[9];
    const float* gam  = (const float*)d_in[10];
    const float* bet  = (const float*)d_in[11];
    const int* tick   = (const int*)d_in[12];

    float* ws = (float*)d_ws;
    float* x  = ws;                      // 32*2304            = 73728 f32
    float* p1 = x  + 73728;              // 2*64*32*512        = 2097152 f32
    float* p2 = p1 + 2097152;            // 2*64*32*512        = 2097152 f32
    float* p3 = p2 + 2097152;            // 4*64*32*256        = 2097152 f32
    float* out = (float*)d_out;

    k_build_x<<<32,  256, 0, stream>>>(emb, pre, Wp, bp, x);
    k_layer1 <<<256, 256, 0, stream>>>(x, W1, p1);
    k_layer2 <<<256, 256, 0, stream>>>(p1, b1, W2, p2);
    k_layer3 <<<256, 256, 0, stream>>>(p2, b2, W3, p3);
    k_final  <<<512, 256, 0, stream>>>(p3, b3, gam, bet, tick, out);
}

// Round 4
// 223.416 us; speedup vs baseline: 2.0205x; 2.0205x over previous
//
#include <hip/hip_runtime.h>
#include <hip/hip_bf16.h>

#define MODEL_DIM 256
#define HIST 8
#define HID 512
#define NNEUR 64
#define IN_DIM 2304   // MODEL_DIM * (1 + HIST)
#define BATCH 32

__device__ __forceinline__ float geluf(float x) {
    return 0.5f * x * (1.0f + erff(x * 0.70710678118654752440f));
}

// ---------------------------------------------------------------------------
// K0: x[b][0:256] = emb[b] @ Wp + bp ; x[b][256:2304] = pre_activations flat
// grid 32 (b), block 256 (d). Output x is f32 in ws.
// ---------------------------------------------------------------------------
__global__ __launch_bounds__(256) void k_build_x(
        const float* __restrict__ emb, const float* __restrict__ pre,
        const float* __restrict__ Wp, const float* __restrict__ bp,
        float* __restrict__ x) {
    const int b = blockIdx.x;
    const int d = threadIdx.x;

    __shared__ float e[MODEL_DIM];
    e[d] = emb[b * MODEL_DIM + d];
    __syncthreads();

    float acc = bp[d];
    #pragma unroll 4
    for (int k = 0; k < MODEL_DIM; ++k)
        acc = fmaf(e[k], Wp[(size_t)k * MODEL_DIM + d], acc);
    x[b * IN_DIM + d] = acc;

    #pragma unroll
    for (int r = 0; r < HIST; ++r)
        x[b * IN_DIM + MODEL_DIM + r * MODEL_DIM + d] = pre[r * MODEL_DIM + d];
}

// ---------------------------------------------------------------------------
// K1: layer1. grid 1024 = n(64) x nt(4: 128 cols) x ks(4: K=576)
// block 256: cg = t&31 (32 x 4 cols = 128), bg = t>>5 (8 x 4 rows = 32)
// K chunks of 192 staged in LDS. p1[4][64][32][512] f32
// ---------------------------------------------------------------------------
__global__ __launch_bounds__(256, 4) void k_layer1(
        const float* __restrict__ x, const float* __restrict__ W1,
        float* __restrict__ p1) {
    const int bid = blockIdx.x;
    const int n  = bid >> 4;
    const int nt = (bid >> 2) & 3;
    const int ks = bid & 3;
    const int t  = threadIdx.x;
    const int cg = t & 31;
    const int bg = t >> 5;
    const int col0  = nt * 128 + cg * 4;
    const int brow0 = bg * 4;

    const float* W = W1 + (size_t)n * IN_DIM * HID;

    float acc[4][4];
    #pragma unroll
    for (int i = 0; i < 4; ++i)
        #pragma unroll
        for (int j = 0; j < 4; ++j) acc[i][j] = 0.0f;

    __shared__ float xs[BATCH][192];
    const int k0 = ks * 576;
    for (int kc = 0; kc < 576; kc += 192) {
        __syncthreads();
        #pragma unroll
        for (int q = 0; q < 6; ++q) {            // 32*48 float4 = 1536
            int fi  = t + 256 * q;
            int row = fi / 48;
            int c4  = fi - row * 48;
            float4 v = *((const float4*)(x + (size_t)row * IN_DIM + k0 + kc + c4 * 4));
            *((float4*)&xs[row][c4 * 4]) = v;
        }
        __syncthreads();
        const float* Wk = W + (size_t)(k0 + kc) * HID + col0;
        #pragma unroll 4
        for (int kk = 0; kk < 192; ++kk) {
            float4 w = *((const float4*)(Wk + (size_t)kk * HID));
            #pragma unroll
            for (int i = 0; i < 4; ++i) {
                float xv = xs[brow0 + i][kk];
                acc[i][0] = fmaf(xv, w.x, acc[i][0]);
                acc[i][1] = fmaf(xv, w.y, acc[i][1]);
                acc[i][2] = fmaf(xv, w.z, acc[i][2]);
                acc[i][3] = fmaf(xv, w.w, acc[i][3]);
            }
        }
    }
    float* P = p1 + (size_t)(ks * NNEUR + n) * BATCH * HID;
    #pragma unroll
    for (int i = 0; i < 4; ++i)
        *((float4*)(P + (size_t)(brow0 + i) * HID + col0)) =
            make_float4(acc[i][0], acc[i][1], acc[i][2], acc[i][3]);
}

// ---------------------------------------------------------------------------
// K2: layer2. h1 = gelu(sum p1[0..3] + b1) staged. grid 1024 = n(64) x nt(8:
// 64 cols) x ks(2: K=256). block: cg = t&15 (16x4 cols), bg = t>>4 (16x2 rows)
// p2[2][64][32][512] f32
// ---------------------------------------------------------------------------
__global__ __launch_bounds__(256, 4) void k_layer2(
        const float* __restrict__ p1, const float* __restrict__ b1,
        const float* __restrict__ W2, float* __restrict__ p2) {
    const int bid = blockIdx.x;
    const int n  = bid >> 4;
    const int nt = (bid >> 1) & 7;
    const int ks = bid & 1;
    const int t  = threadIdx.x;
    const int cg = t & 15;
    const int bg = t >> 4;
    const int col0  = nt * 64 + cg * 4;
    const int brow0 = bg * 2;

    const float* W    = W2 + (size_t)n * HID * HID;
    const float* bias = b1 + (size_t)n * HID;
    const size_t sl = (size_t)NNEUR * BATCH * HID;

    float acc[2][4];
    #pragma unroll
    for (int i = 0; i < 2; ++i)
        #pragma unroll
        for (int j = 0; j < 4; ++j) acc[i][j] = 0.0f;

    __shared__ float xs[BATCH][132];   // pad 4: conflict-free scalar reads
    for (int kc = 0; kc < 256; kc += 128) {
        const int kbase = ks * 256 + kc;
        __syncthreads();
        #pragma unroll
        for (int q = 0; q < 4; ++q) {            // 32*32 float4 = 1024
            int fi  = t + 256 * q;
            int row = fi >> 5;
            int c4  = fi & 31;
            const float* a = p1 + ((size_t)n * BATCH + row) * HID + kbase + c4 * 4;
            float4 v0 = *((const float4*)(a));
            float4 v1 = *((const float4*)(a + sl));
            float4 v2 = *((const float4*)(a + 2 * sl));
            float4 v3 = *((const float4*)(a + 3 * sl));
            float4 bb = *((const float4*)(bias + kbase + c4 * 4));
            *((float4*)&xs[row][c4 * 4]) = make_float4(
                geluf(v0.x + v1.x + v2.x + v3.x + bb.x),
                geluf(v0.y + v1.y + v2.y + v3.y + bb.y),
                geluf(v0.z + v1.z + v2.z + v3.z + bb.z),
                geluf(v0.w + v1.w + v2.w + v3.w + bb.w));
        }
        __syncthreads();
        const float* Wk = W + (size_t)kbase * HID + col0;
        #pragma unroll 8
        for (int kk = 0; kk < 128; ++kk) {
            float4 w = *((const float4*)(Wk + (size_t)kk * HID));
            #pragma unroll
            for (int i = 0; i < 2; ++i) {
                float xv = xs[brow0 + i][kk];
                acc[i][0] = fmaf(xv, w.x, acc[i][0]);
                acc[i][1] = fmaf(xv, w.y, acc[i][1]);
                acc[i][2] = fmaf(xv, w.z, acc[i][2]);
                acc[i][3] = fmaf(xv, w.w, acc[i][3]);
            }
        }
    }
    float* P = p2 + (size_t)(ks * NNEUR + n) * BATCH * HID;
    #pragma unroll
    for (int i = 0; i < 2; ++i)
        *((float4*)(P + (size_t)(brow0 + i) * HID + col0)) =
            make_float4(acc[i][0], acc[i][1], acc[i][2], acc[i][3]);
}

// ---------------------------------------------------------------------------
// K3: layer3. h2 = gelu(p2[0]+p2[1]+b2). grid 512 = n(64) x nt(2: 128 cols)
// x ks(4: K=128). block: cg = t&31 (32x4 cols), bg = t>>5 (8x4 rows)
// p3[4][64][32][256] f32 (aliases p1)
// ---------------------------------------------------------------------------
__global__ __launch_bounds__(256, 4) void k_layer3(
        const float* __restrict__ p2, const float* __restrict__ b2,
        const float* __restrict__ W3, float* __restrict__ p3) {
    const int bid = blockIdx.x;
    const int n  = bid >> 3;
    const int nt = (bid >> 2) & 1;
    const int ks = bid & 3;
    const int t  = threadIdx.x;
    const int cg = t & 31;
    const int bg = t >> 5;
    const int col0  = nt * 128 + cg * 4;
    const int brow0 = bg * 4;

    const float* W    = W3 + (size_t)n * HID * MODEL_DIM;
    const float* bias = b2 + (size_t)n * HID;
    const size_t sl = (size_t)NNEUR * BATCH * HID;
    const int kbase = ks * 128;

    float acc[4][4];
    #pragma unroll
    for (int i = 0; i < 4; ++i)
        #pragma unroll
        for (int j = 0; j < 4; ++j) acc[i][j] = 0.0f;

    __shared__ float xs[BATCH][128];
    #pragma unroll
    for (int q = 0; q < 4; ++q) {
        int fi  = t + 256 * q;
        int row = fi >> 5;
        int c4  = fi & 31;
        const float* a = p2 + ((size_t)n * BATCH + row) * HID + kbase + c4 * 4;
        float4 v0 = *((const float4*)(a));
        float4 v1 = *((const float4*)(a + sl));
        float4 bb = *((const float4*)(bias + kbase + c4 * 4));
        *((float4*)&xs[row][c4 * 4]) = make_float4(
            geluf(v0.x + v1.x + bb.x),
            geluf(v0.y + v1.y + bb.y),
            geluf(v0.z + v1.z + bb.z),
            geluf(v0.w + v1.w + bb.w));
    }
    __syncthreads();
    const float* Wk = W + (size_t)kbase * MODEL_DIM + col0;
    #pragma unroll 4
    for (int kk = 0; kk < 128; ++kk) {
        float4 w = *((const float4*)(Wk + (size_t)kk * MODEL_DIM));
        #pragma unroll
        for (int i = 0; i < 4; ++i) {
            float xv = xs[brow0 + i][kk];
            acc[i][0] = fmaf(xv, w.x, acc[i][0]);
            acc[i][1] = fmaf(xv, w.y, acc[i][1]);
            acc[i][2] = fmaf(xv, w.z, acc[i][2]);
            acc[i][3] = fmaf(xv, w.w, acc[i][3]);
        }
    }
    float* P = p3 + (size_t)(ks * NNEUR + n) * BATCH * MODEL_DIM;
    #pragma unroll
    for (int i = 0; i < 4; ++i)
        *((float4*)(P + (size_t)(brow0 + i) * MODEL_DIM + col0)) =
            make_float4(acc[i][0], acc[i][1], acc[i][2], acc[i][3]);
}

// ---------------------------------------------------------------------------
// K4: y = sum(p3[0..3]) + b3 ; LayerNorm ; oscillator mod ; f32 store
// grid 512 = n(64) x bquad(8); block 256 = 4 waves, wave w -> batch row
// ---------------------------------------------------------------------------
__global__ __launch_bounds__(256) void k_final(
        const float* __restrict__ p3, const float* __restrict__ b3,
        const float* __restrict__ gamma, const float* __restrict__ beta,
        const int* __restrict__ tick, float* __restrict__ out) {
    const int n  = blockIdx.x >> 3;
    const int bq = blockIdx.x & 7;
    const int t  = threadIdx.x;
    const int w  = t >> 6;
    const int lane = t & 63;
    const int b  = bq * 4 + w;

    const size_t par0 = (size_t)n * MODEL_DIM;
    const size_t rowoff = ((size_t)n * BATCH + b) * MODEL_DIM;
    const size_t sl = (size_t)NNEUR * BATCH * MODEL_DIM;

    float y[4];
    #pragma unroll
    for (int j = 0; j < 4; ++j) {
        int d = lane + 64 * j;
        float v = b3[par0 + d];
        v += p3[rowoff + d];
        v += p3[sl + rowoff + d];
        v += p3[2 * sl + rowoff + d];
        v += p3[3 * sl + rowoff + d];
        y[j] = v;
    }
    float s = y[0] + y[1] + y[2] + y[3];
    #pragma unroll
    for (int off = 32; off > 0; off >>= 1) s += __shfl_xor(s, off);
    float mu = s * (1.0f / 256.0f);
    float q = 0.0f;
    #pragma unroll
    for (int j = 0; j < 4; ++j) { float d0 = y[j] - mu; q = fmaf(d0, d0, q); }
    #pragma unroll
    for (int off = 32; off > 0; off >>= 1) q += __shfl_xor(q, off);
    float inv = rsqrtf(q * (1.0f / 256.0f) + 1e-5f);

    const double TWO_PI = 6.283185307179586476925287;
    double freq  = 0.5 * pow(80.0, (double)n * (1.0 / 63.0));
    double phase = fmod((double)n * 2.3571, TWO_PI);
    double tt    = (double)(*tick) * 0.1;
    float mod = (float)(1.0 + 0.5 * sin(TWO_PI * freq * tt + phase));

    #pragma unroll
    for (int j = 0; j < 4; ++j) {
        int d = lane + 64 * j;
        float o = (y[j] - mu) * inv * gamma[par0 + d] + beta[par0 + d];
        o *= mod;
        out[((size_t)b * NNEUR + n) * MODEL_DIM + d] = o;
    }
}

// ---------------------------------------------------------------------------
extern "C" void kernel_launch(void* const* d_in, const int* in_sizes, int n_in,
                              void* d_out, int out_size, void* d_ws, size_t ws_size,
                              hipStream_t stream) {
    const float* emb  = (const float*)d_in[0];
    const float* pre  = (const float*)d_in[1];
    const float* Wp   = (const float*)d_in[2];
    const float* bp   = (const float*)d_in[3];
    const float* W1   = (const float*)d_in[4];
    const float* b1   = (const float*)d_in[5];
    const float* W2   = (const float*)d_in[6];
    const float* b2   = (const float*)d_in[7];
    const float* W3   = (const float*)d_in[8];
    const float* b3   = (const float*)d_in[9];
    const float* gam  = (const float*)d_in[10];
    const float* bet  = (const float*)d_in[11];
    const int* tick   = (const int*)d_in[12];

    float* ws = (float*)d_ws;
    float* x  = ws;                      // 32*2304          =   73728 f32
    float* p1 = x  + 73728;              // [4][64][32][512] = 4194304 f32
    float* p2 = p1 + 4194304;            // [2][64][32][512] = 2097152 f32
    float* p3 = p1;                      // [4][64][32][256] = 2097152 f32 (aliases dead p1)
    float* out = (float*)d_out;

    k_build_x<<<32,   256, 0, stream>>>(emb, pre, Wp, bp, x);
    k_layer1 <<<1024, 256, 0, stream>>>(x, W1, p1);
    k_layer2 <<<1024, 256, 0, stream>>>(p1, b1, W2, p2);
    k_layer3 <<<512,  256, 0, stream>>>(p2, b2, W3, p3);
    k_final  <<<512,  256, 0, stream>>>(p3, b3, gam, bet, tick, out);
}

// Round 5
// 195.550 us; speedup vs baseline: 2.3085x; 1.1425x over previous
//
#include <hip/hip_runtime.h>
#include <hip/hip_bf16.h>

#define MODEL_DIM 256
#define HIST 8
#define HID 512
#define NNEUR 64
#define IN_DIM 2304   // MODEL_DIM * (1 + HIST)
#define BATCH 32

__device__ __forceinline__ float geluf(float x) {
    return 0.5f * x * (1.0f + erff(x * 0.70710678118654752440f));
}

// ---------------------------------------------------------------------------
// K0: x[b][0:256] = emb[b] @ Wp + bp ; x[b][256:2304] = pre_activations flat
// grid 32 (b), block 256 (d).
// ---------------------------------------------------------------------------
__global__ __launch_bounds__(256) void k_build_x(
        const float* __restrict__ emb, const float* __restrict__ pre,
        const float* __restrict__ Wp, const float* __restrict__ bp,
        float* __restrict__ x) {
    const int b = blockIdx.x;
    const int d = threadIdx.x;

    __shared__ float e[MODEL_DIM];
    e[d] = emb[b * MODEL_DIM + d];
    __syncthreads();

    float acc = bp[d];
    #pragma unroll 4
    for (int k = 0; k < MODEL_DIM; ++k)
        acc = fmaf(e[k], Wp[(size_t)k * MODEL_DIM + d], acc);
    x[b * IN_DIM + d] = acc;

    #pragma unroll
    for (int r = 0; r < HIST; ++r)
        x[b * IN_DIM + MODEL_DIM + r * MODEL_DIM + d] = pre[r * MODEL_DIM + d];
}

// ---------------------------------------------------------------------------
// K1: layer1. grid 512 = n(64) x ks(8: K=288). block 512 = 8 waves.
// thread: cg = t&127 -> 4 cols (full 512 via 128 cg), rg = t>>7 -> 8 rows.
// Wave lanes span 256 contiguous cols = 1KB unique coalesced W per kk.
// x K-slice staged once in LDS; reads are wave-uniform broadcasts.
// p1[8][64][32][512] f32
// ---------------------------------------------------------------------------
__global__ __launch_bounds__(512, 4) void k_layer1(
        const float* __restrict__ x, const float* __restrict__ W1,
        float* __restrict__ p1) {
    const int n  = blockIdx.x >> 3;
    const int ks = blockIdx.x & 7;
    const int t  = threadIdx.x;
    const int cg = t & 127;
    const int rg = t >> 7;
    const int col0 = cg * 4;
    const int row0 = rg * 8;
    const int k0 = ks * 288;

    __shared__ float xs[BATCH][288];
    #pragma unroll
    for (int q = 0; q < 5; ++q) {                 // 32*72 float4 = 2304
        int fi = t + 512 * q;
        if (fi < 2304) {
            int row = fi / 72;
            int c4  = fi - row * 72;
            *((float4*)&xs[row][c4 * 4]) =
                *((const float4*)(x + (size_t)row * IN_DIM + k0 + c4 * 4));
        }
    }
    __syncthreads();

    const float* W = W1 + (size_t)n * IN_DIM * HID + (size_t)k0 * HID + col0;

    float acc[8][4];
    #pragma unroll
    for (int i = 0; i < 8; ++i)
        #pragma unroll
        for (int j = 0; j < 4; ++j) acc[i][j] = 0.0f;

    #pragma unroll 4
    for (int kk = 0; kk < 288; ++kk) {
        float4 w = *((const float4*)(W + (size_t)kk * HID));
        #pragma unroll
        for (int i = 0; i < 8; ++i) {
            float xv = xs[row0 + i][kk];
            acc[i][0] = fmaf(xv, w.x, acc[i][0]);
            acc[i][1] = fmaf(xv, w.y, acc[i][1]);
            acc[i][2] = fmaf(xv, w.z, acc[i][2]);
            acc[i][3] = fmaf(xv, w.w, acc[i][3]);
        }
    }
    float* P = p1 + (size_t)(ks * NNEUR + n) * BATCH * HID;
    #pragma unroll
    for (int i = 0; i < 8; ++i)
        *((float4*)(P + (size_t)(row0 + i) * HID + col0)) =
            make_float4(acc[i][0], acc[i][1], acc[i][2], acc[i][3]);
}

// ---------------------------------------------------------------------------
// K2: layer2. h1 = gelu(sum p1[0..7] + b1) staged once per block.
// grid 512 = n(64) x ch(2: 256 cols) x ks(4: K=128). block 512.
// thread: cg = t&63 -> 4 cols, rg = t>>6 -> 4 rows. p2[4][64][32][512] f32
// ---------------------------------------------------------------------------
__global__ __launch_bounds__(512, 4) void k_layer2(
        const float* __restrict__ p1, const float* __restrict__ b1,
        const float* __restrict__ W2, float* __restrict__ p2) {
    const int bid = blockIdx.x;
    const int n  = bid >> 3;
    const int ch = (bid >> 2) & 1;
    const int ks = bid & 3;
    const int t  = threadIdx.x;
    const int cg = t & 63;
    const int rg = t >> 6;
    const int col0 = ch * 256 + cg * 4;
    const int row0 = rg * 4;
    const int k0 = ks * 128;

    const size_t sl = (size_t)NNEUR * BATCH * HID;

    __shared__ float xs[BATCH][128];
    #pragma unroll
    for (int q = 0; q < 2; ++q) {                 // 32*32 float4 = 1024
        int fi  = t + 512 * q;
        int row = fi >> 5;
        int c4  = fi & 31;
        const float* a = p1 + ((size_t)n * BATCH + row) * HID + k0 + c4 * 4;
        float4 s0 = *((const float4*)(a));
        float4 s1 = *((const float4*)(a + sl));
        float4 s2 = *((const float4*)(a + 2 * sl));
        float4 s3 = *((const float4*)(a + 3 * sl));
        float4 s4 = *((const float4*)(a + 4 * sl));
        float4 s5 = *((const float4*)(a + 5 * sl));
        float4 s6 = *((const float4*)(a + 6 * sl));
        float4 s7 = *((const float4*)(a + 7 * sl));
        float4 bb = *((const float4*)(b1 + (size_t)n * HID + k0 + c4 * 4));
        *((float4*)&xs[row][c4 * 4]) = make_float4(
            geluf(s0.x+s1.x+s2.x+s3.x+s4.x+s5.x+s6.x+s7.x + bb.x),
            geluf(s0.y+s1.y+s2.y+s3.y+s4.y+s5.y+s6.y+s7.y + bb.y),
            geluf(s0.z+s1.z+s2.z+s3.z+s4.z+s5.z+s6.z+s7.z + bb.z),
            geluf(s0.w+s1.w+s2.w+s3.w+s4.w+s5.w+s6.w+s7.w + bb.w));
    }
    __syncthreads();

    const float* W = W2 + (size_t)n * HID * HID + (size_t)k0 * HID + col0;

    float acc[4][4];
    #pragma unroll
    for (int i = 0; i < 4; ++i)
        #pragma unroll
        for (int j = 0; j < 4; ++j) acc[i][j] = 0.0f;

    #pragma unroll 4
    for (int kk = 0; kk < 128; ++kk) {
        float4 w = *((const float4*)(W + (size_t)kk * HID));
        #pragma unroll
        for (int i = 0; i < 4; ++i) {
            float xv = xs[row0 + i][kk];
            acc[i][0] = fmaf(xv, w.x, acc[i][0]);
            acc[i][1] = fmaf(xv, w.y, acc[i][1]);
            acc[i][2] = fmaf(xv, w.z, acc[i][2]);
            acc[i][3] = fmaf(xv, w.w, acc[i][3]);
        }
    }
    float* P = p2 + (size_t)(ks * NNEUR + n) * BATCH * HID;
    #pragma unroll
    for (int i = 0; i < 4; ++i)
        *((float4*)(P + (size_t)(row0 + i) * HID + col0)) =
            make_float4(acc[i][0], acc[i][1], acc[i][2], acc[i][3]);
}

// ---------------------------------------------------------------------------
// K3: layer3. h2 = gelu(sum p2[0..3] + b2) staged once per block.
// grid 512 = n(64) x ks(8: K=64). block 512.
// thread: cg = t&63 -> 4 cols (full 256), rg = t>>6 -> 4 rows.
// p3[8][64][32][256] f32 (aliases p1)
// ---------------------------------------------------------------------------
__global__ __launch_bounds__(512, 4) void k_layer3(
        const float* __restrict__ p2, const float* __restrict__ b2,
        const float* __restrict__ W3, float* __restrict__ p3) {
    const int n  = blockIdx.x >> 3;
    const int ks = blockIdx.x & 7;
    const int t  = threadIdx.x;
    const int cg = t & 63;
    const int rg = t >> 6;
    const int col0 = cg * 4;
    const int row0 = rg * 4;
    const int k0 = ks * 64;

    const size_t sl = (size_t)NNEUR * BATCH * HID;

    __shared__ float xs[BATCH][64];
    {                                             // 32*16 float4 = 512
        int row = t >> 4;
        int c4  = t & 15;
        const float* a = p2 + ((size_t)n * BATCH + row) * HID + k0 + c4 * 4;
        float4 s0 = *((const float4*)(a));
        float4 s1 = *((const float4*)(a + sl));
        float4 s2 = *((const float4*)(a + 2 * sl));
        float4 s3 = *((const float4*)(a + 3 * sl));
        float4 bb = *((const float4*)(b2 + (size_t)n * HID + k0 + c4 * 4));
        *((float4*)&xs[row][c4 * 4]) = make_float4(
            geluf(s0.x+s1.x+s2.x+s3.x + bb.x),
            geluf(s0.y+s1.y+s2.y+s3.y + bb.y),
            geluf(s0.z+s1.z+s2.z+s3.z + bb.z),
            geluf(s0.w+s1.w+s2.w+s3.w + bb.w));
    }
    __syncthreads();

    const float* W = W3 + (size_t)n * HID * MODEL_DIM + (size_t)k0 * MODEL_DIM + col0;

    float acc[4][4];
    #pragma unroll
    for (int i = 0; i < 4; ++i)
        #pragma unroll
        for (int j = 0; j < 4; ++j) acc[i][j] = 0.0f;

    #pragma unroll 4
    for (int kk = 0; kk < 64; ++kk) {
        float4 w = *((const float4*)(W + (size_t)kk * MODEL_DIM));
        #pragma unroll
        for (int i = 0; i < 4; ++i) {
            float xv = xs[row0 + i][kk];
            acc[i][0] = fmaf(xv, w.x, acc[i][0]);
            acc[i][1] = fmaf(xv, w.y, acc[i][1]);
            acc[i][2] = fmaf(xv, w.z, acc[i][2]);
            acc[i][3] = fmaf(xv, w.w, acc[i][3]);
        }
    }
    float* P = p3 + (size_t)(ks * NNEUR + n) * BATCH * MODEL_DIM;
    #pragma unroll
    for (int i = 0; i < 4; ++i)
        *((float4*)(P + (size_t)(row0 + i) * MODEL_DIM + col0)) =
            make_float4(acc[i][0], acc[i][1], acc[i][2], acc[i][3]);
}

// ---------------------------------------------------------------------------
// K4: y = sum(p3[0..7]) + b3 ; LayerNorm ; oscillator mod ; f32 store
// grid 512 = n(64) x bquad(8); block 256 = 4 waves, wave w -> batch row
// ---------------------------------------------------------------------------
__global__ __launch_bounds__(256) void k_final(
        const float* __restrict__ p3, const float* __restrict__ b3,
        const float* __restrict__ gamma, const float* __restrict__ beta,
        const int* __restrict__ tick, float* __restrict__ out) {
    const int n  = blockIdx.x >> 3;
    const int bq = blockIdx.x & 7;
    const int t  = threadIdx.x;
    const int w  = t >> 6;
    const int lane = t & 63;
    const int b  = bq * 4 + w;

    const size_t par0 = (size_t)n * MODEL_DIM;
    const size_t rowoff = ((size_t)n * BATCH + b) * MODEL_DIM;
    const size_t sl = (size_t)NNEUR * BATCH * MODEL_DIM;

    float y[4];
    #pragma unroll
    for (int j = 0; j < 4; ++j) {
        int d = lane + 64 * j;
        float v = b3[par0 + d];
        #pragma unroll
        for (int s = 0; s < 8; ++s)
            v += p3[s * sl + rowoff + d];
        y[j] = v;
    }
    float s = y[0] + y[1] + y[2] + y[3];
    #pragma unroll
    for (int off = 32; off > 0; off >>= 1) s += __shfl_xor(s, off);
    float mu = s * (1.0f / 256.0f);
    float q = 0.0f;
    #pragma unroll
    for (int j = 0; j < 4; ++j) { float d0 = y[j] - mu; q = fmaf(d0, d0, q); }
    #pragma unroll
    for (int off = 32; off > 0; off >>= 1) q += __shfl_xor(q, off);
    float inv = rsqrtf(q * (1.0f / 256.0f) + 1e-5f);

    const double TWO_PI = 6.283185307179586476925287;
    double freq  = 0.5 * pow(80.0, (double)n * (1.0 / 63.0));
    double phase = fmod((double)n * 2.3571, TWO_PI);
    double tt    = (double)(*tick) * 0.1;
    float mod = (float)(1.0 + 0.5 * sin(TWO_PI * freq * tt + phase));

    #pragma unroll
    for (int j = 0; j < 4; ++j) {
        int d = lane + 64 * j;
        float o = (y[j] - mu) * inv * gamma[par0 + d] + beta[par0 + d];
        o *= mod;
        out[((size_t)b * NNEUR + n) * MODEL_DIM + d] = o;
    }
}

// ---------------------------------------------------------------------------
extern "C" void kernel_launch(void* const* d_in, const int* in_sizes, int n_in,
                              void* d_out, int out_size, void* d_ws, size_t ws_size,
                              hipStream_t stream) {
    const float* emb  = (const float*)d_in[0];
    const float* pre  = (const float*)d_in[1];
    const float* Wp   = (const float*)d_in[2];
    const float* bp   = (const float*)d_in[3];
    const float* W1   = (const float*)d_in[4];
    const float* b1   = (const float*)d_in[5];
    const float* W2   = (const float*)d_in[6];
    const float* b2   = (const float*)d_in[7];
    const float* W3   = (const float*)d_in[8];
    const float* b3   = (const float*)d_in[9];
    const float* gam  = (const float*)d_in[10];
    const float* bet  = (const float*)d_in[11];
    const int* tick   = (const int*)d_in[12];

    float* ws = (float*)d_ws;
    float* x  = ws;                      // 32*2304          =   73728 f32
    float* p1 = x  + 73728;              // [8][64][32][512] = 8388608 f32
    float* p2 = p1 + 8388608;            // [4][64][32][512] = 4194304 f32
    float* p3 = p1;                      // [8][64][32][256] = 4194304 f32 (aliases dead p1)
    float* out = (float*)d_out;

    k_build_x<<<32,  256, 0, stream>>>(emb, pre, Wp, bp, x);
    k_layer1 <<<512, 512, 0, stream>>>(x, W1, p1);
    k_layer2 <<<512, 512, 0, stream>>>(p1, b1, W2, p2);
    k_layer3 <<<512, 512, 0, stream>>>(p2, b2, W3, p3);
    k_final  <<<512, 256, 0, stream>>>(p3, b3, gam, bet, tick, out);
}